// Round 1
// baseline (357.913 us; speedup 1.0000x reference)
//
#include <hip/hip_runtime.h>
#include <hip/hip_bf16.h>
#include <math.h>

// Problem constants
#define BB 4096
#define DD 2048
#define HH 2048
// block-diagonal: 4 blocks of 512x512 per gate matmul

typedef __bf16 bf16x8 __attribute__((ext_vector_type(8)));
typedef float f32x16 __attribute__((ext_vector_type(16)));

__device__ __forceinline__ void async16(const void* g, void* l) {
  __builtin_amdgcn_global_load_lds(
      (const __attribute__((address_space(1))) unsigned int*)g,
      (__attribute__((address_space(3))) unsigned int*)l,
      16, 0, 0);
}

__device__ __forceinline__ float sigmoidf_(float x) {
  return 1.0f / (1.0f + __expf(-x));
}

// ---------------------------------------------------------------------------
// bias[g][c] = b_g[c] + rb_g[c],  g in {z,i,f,o}, c in [0,2048)
__global__ void prep_bias(const float* __restrict__ bz, const float* __restrict__ bi,
                          const float* __restrict__ bf, const float* __restrict__ bo,
                          const float* __restrict__ rbz, const float* __restrict__ rbi,
                          const float* __restrict__ rbf, const float* __restrict__ rbo,
                          float* __restrict__ bias) {
  int i = blockIdx.x * 256 + threadIdx.x;
  if (i < 2048) {
    bias[0 * 2048 + i] = bz[i] + rbz[i];
    bias[1 * 2048 + i] = bi[i] + rbi[i];
    bias[2 * 2048 + i] = bf[i] + rbf[i];
    bias[3 * 2048 + i] = bo[i] + rbo[i];
  }
}

// ---------------------------------------------------------------------------
// WT[((g*4+n)*512 + j)*1024 + kt], kt<512 -> W_g[n][kt][j], kt>=512 -> R_g[n][kt-512][j]
// bf16 cast, k-contiguous so GEMM B-tiles are straight contiguous copies.
__global__ void prep_w(const float* __restrict__ Wz, const float* __restrict__ Wi,
                       const float* __restrict__ Wf, const float* __restrict__ Wo,
                       const float* __restrict__ Rz, const float* __restrict__ Ri,
                       const float* __restrict__ Rf, const float* __restrict__ Ro,
                       __hip_bfloat16* __restrict__ WT) {
  int jt = blockIdx.x;         // 16 tiles of 32 over j
  int ktt = blockIdx.y;        // 32 tiles of 32 over kt in [0,1024)
  int gn = blockIdx.z;         // g*4 + n
  int g = gn >> 2, nn = gn & 3;
  int ktg0 = ktt * 32;
  const float* src;
  if (ktg0 < 512) src = (g == 0 ? Wz : g == 1 ? Wi : g == 2 ? Wf : Wo);
  else            src = (g == 0 ? Rz : g == 1 ? Ri : g == 2 ? Rf : Ro);
  int ks0 = ktg0 & 511;
  int j0 = jt * 32;
  __shared__ float tile[32][33];
  int tx = threadIdx.x, ty = threadIdx.y;  // 32 x 8
#pragma unroll
  for (int r = 0; r < 4; r++) {
    int kk = ty + r * 8;
    tile[kk][tx] = src[((size_t)nn * 512 + ks0 + kk) * 512 + j0 + tx];
  }
  __syncthreads();
#pragma unroll
  for (int r = 0; r < 4; r++) {
    int jj = ty + r * 8;
    WT[((size_t)gn * 512 + j0 + jj) * 1024 + ktg0 + tx] = __float2bfloat16(tile[tx][jj]);
  }
}

// ---------------------------------------------------------------------------
// Per row: LayerNorm -> causal conv3 -> SiLU; emit bf16 x, x_conv, h_prev.
__global__ __launch_bounds__(256) void prep_act(
    const float* __restrict__ x, const float* __restrict__ h,
    const float* __restrict__ lg, const float* __restrict__ lb,
    const float* __restrict__ cw, const float* __restrict__ cb,
    __hip_bfloat16* __restrict__ xb, __hip_bfloat16* __restrict__ xcb,
    __hip_bfloat16* __restrict__ hb) {
  int row = blockIdx.x;
  int t = threadIdx.x;
  __shared__ float xn[2048];
  __shared__ float red[8];
  const float* xr = x + (size_t)row * 2048;
  const float* hr = h + (size_t)row * 2048;
  float4 v0 = ((const float4*)xr)[t * 2];
  float4 v1 = ((const float4*)xr)[t * 2 + 1];
  float vv[8] = {v0.x, v0.y, v0.z, v0.w, v1.x, v1.y, v1.z, v1.w};
  float s = 0.f, s2 = 0.f;
#pragma unroll
  for (int e = 0; e < 8; e++) { s += vv[e]; s2 += vv[e] * vv[e]; }
#pragma unroll
  for (int off = 32; off > 0; off >>= 1) {
    s += __shfl_down(s, off);
    s2 += __shfl_down(s2, off);
  }
  int w = t >> 6, l = t & 63;
  if (l == 0) { red[w] = s; red[4 + w] = s2; }
  __syncthreads();
  float mu = (red[0] + red[1] + red[2] + red[3]) * (1.0f / 2048.0f);
  float var = (red[4] + red[5] + red[6] + red[7]) * (1.0f / 2048.0f) - mu * mu;
  float rs = rsqrtf(var + 1e-5f);

  float4 h0 = ((const float4*)hr)[t * 2];
  float4 h1 = ((const float4*)hr)[t * 2 + 1];
  float hh[8] = {h0.x, h0.y, h0.z, h0.w, h1.x, h1.y, h1.z, h1.w};
  int j0 = t * 8;
#pragma unroll
  for (int e = 0; e < 8; e++) {
    int j = j0 + e;
    xn[j] = (vv[e] - mu) * rs * lg[j] + lb[j];
    xb[(size_t)row * 2048 + j] = __float2bfloat16(vv[e]);
    hb[(size_t)row * 2048 + j] = __float2bfloat16(hh[e]);
  }
  __syncthreads();
  float w0 = cw[0], w1 = cw[1], w2 = cw[2], bbv = cb[0];
#pragma unroll
  for (int e = 0; e < 8; e++) {
    int j = j0 + e;
    float a0 = (j >= 2) ? xn[j - 2] : 0.f;
    float a1 = (j >= 1) ? xn[j - 1] : 0.f;
    float xc = w0 * a0 + w1 * a1 + w2 * xn[j] + bbv;
    float sc = xc * sigmoidf_(xc);
    xcb[(size_t)row * 2048 + j] = __float2bfloat16(sc);
  }
}

// ---------------------------------------------------------------------------
// Fused 4-gate block GEMM + sLSTM pointwise epilogue.
// Grid: (4096/64, 512/64, 4). Block: 256 threads = 4 waves in 2x2.
// Each wave: one 32x32 output tile per gate (4x f32x16 acc).
// K-loop: kt in [0,1024) step 32. kt<512: A1=x (z,o), A2=x_conv (i,f).
//         kt>=512: A1=A2=h. B from WT (k-contiguous, gates 0..3 = z,i,f,o).
__global__ __launch_bounds__(256, 2) void gemm_fused(
    const __hip_bfloat16* __restrict__ xb, const __hip_bfloat16* __restrict__ xcb,
    const __hip_bfloat16* __restrict__ hb, const __hip_bfloat16* __restrict__ WT,
    const float* __restrict__ bias, const float* __restrict__ c_prev,
    float* __restrict__ out) {
  __shared__ alignas(16) __hip_bfloat16 As1[64 * 32];
  __shared__ alignas(16) __hip_bfloat16 As2[64 * 32];
  __shared__ alignas(16) __hip_bfloat16 Bs[4][64 * 32];

  const int m0 = blockIdx.x * 64;
  const int j0 = blockIdx.y * 64;
  const int n = blockIdx.z;
  const int t = threadIdx.x;
  const int w = t >> 6, l = t & 63;
  const int wr = w >> 1, wc = w & 1;

  f32x16 accZ = {}, accI = {}, accF = {}, accO = {};

  // A staging: thread t covers element offset t*8 of the [64][32] tile.
  const size_t a_goff = (size_t)(m0 + (t >> 2)) * 2048 + (size_t)n * 512 + (size_t)((t & 3) * 8);
  char* As1w = (char*)As1 + w * 1024;
  char* As2w = (char*)As2 + w * 1024;
  // B staging: wave w stages gate w's [64][32] tile (4 chunks of 1KB).
  const size_t b_gbase = ((size_t)(w * 4 + n) * 512 + j0) * 1024;
  char* Bw = (char*)Bs[w];

  // fragment offsets (elements), kh adds 16
  const int a_eoff = (wr * 32 + (l & 31)) * 32 + ((l >> 5) * 8);
  const int b_eoff = (wc * 32 + (l & 31)) * 32 + ((l >> 5) * 8);

  for (int ks = 0; ks < 32; ++ks) {
    const int kt = ks * 32;
    const bool ph0 = (kt < 512);
    const __hip_bfloat16* a1 = ph0 ? xb : hb;
    const __hip_bfloat16* a2 = ph0 ? xcb : hb;
    const int kk = kt & 511;

    __syncthreads();
    async16(a1 + a_goff + kk, As1w);
    async16(a2 + a_goff + kk, As2w);
#pragma unroll
    for (int q = 0; q < 4; ++q) {
      int idx = q * 64 + l;
      async16(WT + b_gbase + (size_t)(idx >> 2) * 1024 + kt + (idx & 3) * 8,
              Bw + q * 1024);
    }
    __syncthreads();

#pragma unroll
    for (int kh = 0; kh < 2; ++kh) {
      bf16x8 a1f = *(const bf16x8*)(As1 + a_eoff + kh * 16);
      bf16x8 a2f = *(const bf16x8*)(As2 + a_eoff + kh * 16);
      bf16x8 bzf = *(const bf16x8*)(Bs[0] + b_eoff + kh * 16);
      bf16x8 bif = *(const bf16x8*)(Bs[1] + b_eoff + kh * 16);
      bf16x8 bff = *(const bf16x8*)(Bs[2] + b_eoff + kh * 16);
      bf16x8 bof = *(const bf16x8*)(Bs[3] + b_eoff + kh * 16);
      accZ = __builtin_amdgcn_mfma_f32_32x32x16_bf16(a1f, bzf, accZ, 0, 0, 0);
      accI = __builtin_amdgcn_mfma_f32_32x32x16_bf16(a2f, bif, accI, 0, 0, 0);
      accF = __builtin_amdgcn_mfma_f32_32x32x16_bf16(a2f, bff, accF, 0, 0, 0);
      accO = __builtin_amdgcn_mfma_f32_32x32x16_bf16(a1f, bof, accO, 0, 0, 0);
    }
  }

  // Epilogue. C/D layout (32x32): col = lane&31, row = (r&3) + 8*(r>>2) + 4*(lane>>5)
  const int col = n * 512 + j0 + wc * 32 + (l & 31);
  const float bz_ = bias[0 * 2048 + col];
  const float bi_ = bias[1 * 2048 + col];
  const float bf_ = bias[2 * 2048 + col];
  const float bo_ = bias[3 * 2048 + col];
  const size_t HC = (size_t)BB * HH;
#pragma unroll
  for (int r = 0; r < 16; ++r) {
    int row = m0 + wr * 32 + (r & 3) + 8 * (r >> 2) + 4 * (l >> 5);
    float z = tanhf(accZ[r] + bz_);
    float ig = sigmoidf_(accI[r] + bi_);
    float fg = sigmoidf_(accF[r] + bf_);
    float og = sigmoidf_(accO[r] + bo_);
    float cp = c_prev[(size_t)row * 2048 + col];
    float c = fg * cp + ig * z;
    float hv = og * tanhf(c);
    out[(size_t)row * 2048 + col] = hv;
    out[HC + (size_t)row * 2048 + col] = c;
  }
}

// ---------------------------------------------------------------------------
extern "C" void kernel_launch(void* const* d_in, const int* in_sizes, int n_in,
                              void* d_out, int out_size, void* d_ws, size_t ws_size,
                              hipStream_t stream) {
  const float* x      = (const float*)d_in[0];
  const float* h_prev = (const float*)d_in[1];
  const float* c_prev = (const float*)d_in[2];
  const float* ln_g   = (const float*)d_in[3];
  const float* ln_b   = (const float*)d_in[4];
  const float* conv_w = (const float*)d_in[5];
  const float* conv_b = (const float*)d_in[6];
  const float* Wz = (const float*)d_in[7];
  const float* bz = (const float*)d_in[8];
  const float* Wi = (const float*)d_in[9];
  const float* bi = (const float*)d_in[10];
  const float* Wf = (const float*)d_in[11];
  const float* bf = (const float*)d_in[12];
  const float* Wo = (const float*)d_in[13];
  const float* bo = (const float*)d_in[14];
  const float* Rz = (const float*)d_in[15];
  const float* rbz = (const float*)d_in[16];
  const float* Ri = (const float*)d_in[17];
  const float* rbi = (const float*)d_in[18];
  const float* Rf = (const float*)d_in[19];
  const float* rbf = (const float*)d_in[20];
  const float* Ro = (const float*)d_in[21];
  const float* rbo = (const float*)d_in[22];
  float* out = (float*)d_out;

  char* ws = (char*)d_ws;
  const size_t SZ = (size_t)BB * DD * sizeof(__hip_bfloat16);  // 16 MiB
  __hip_bfloat16* xb  = (__hip_bfloat16*)(ws);
  __hip_bfloat16* xcb = (__hip_bfloat16*)(ws + SZ);
  __hip_bfloat16* hb  = (__hip_bfloat16*)(ws + 2 * SZ);
  __hip_bfloat16* WT  = (__hip_bfloat16*)(ws + 3 * SZ);   // 4*4*512*1024*2 = 16 MiB
  float* bias         = (float*)(ws + 4 * SZ);            // 4*2048*4 = 32 KiB

  prep_bias<<<8, 256, 0, stream>>>(bz, bi, bf, bo, rbz, rbi, rbf, rbo, bias);
  prep_w<<<dim3(16, 32, 16), dim3(32, 8), 0, stream>>>(Wz, Wi, Wf, Wo, Rz, Ri, Rf, Ro, WT);
  prep_act<<<BB, 256, 0, stream>>>(x, h_prev, ln_g, ln_b, conv_w, conv_b, xb, xcb, hb);
  gemm_fused<<<dim3(BB / 64, 512 / 64, 4), 256, 0, stream>>>(xb, xcb, hb, WT, bias, c_prev, out);
}